// Round 1
// 465.930 us; speedup vs baseline: 1.0020x; 1.0020x over previous
//
#include <hip/hip_runtime.h>

// Cosine similarity per row: q,d are [N, 256] fp32; out is [N] fp32.
//
// R(this): 16 lanes per row, 4 rows per wave, 4 fx4 chunks per lane.
// Each lane accumulates qq/dd/qd over its 4 chunks in registers (VALU,
// no cross-lane), then a 4-step xor butterfly (offsets 8,4,2,1 -- stays
// inside the 16-lane group) finishes the row reduction. vs the previous
// 64-lane-per-row version this is 6x fewer cross-lane ops per byte
// (12 per 8 KiB instead of 36 per 4 KiB), a 4-deep instead of 6-deep
// dependent swizzle chain, and 8 loads in flight per lane instead of 4.
// Inputs streamed exactly once -> nontemporal loads/stores.
// Memory floor: 512 MiB in, 1 MiB out -> ~85 us at 6.3 TB/s.
//
// Note: __builtin_nontemporal_load requires native clang vector types,
// not HIP_vector_type structs -> ext_vector_type.
typedef float fx4 __attribute__((ext_vector_type(4)));

constexpr int ROWS_PER_WAVE = 4;   // 64 lanes / 16 lanes-per-row
constexpr int WAVES_PER_BLOCK = 4; // 256 threads

__global__ __launch_bounds__(256) void cosine_rows_kernel(
    const fx4* __restrict__ q4,   // [N, 64] fx4 view of [N,256] f32
    const fx4* __restrict__ d4,
    float* __restrict__ out,      // [N] f32
    int n_rows)
{
    const int wave = (blockIdx.x * blockDim.x + threadIdx.x) >> 6;
    const int lane = threadIdx.x & 63;
    const int g    = lane >> 4;    // which of the wave's 4 rows
    const int c    = lane & 15;    // chunk lane within the row
    const int row  = wave * ROWS_PER_WAVE + g;
    if (row >= n_rows) return;

    // Row has 64 fx4 chunks; this lane takes chunks c, c+16, c+32, c+48.
    // Per load instruction a 16-lane group covers one contiguous 256 B
    // segment of its row; 8 independent loads issued back-to-back.
    const size_t base = (size_t)row * 64 + c;

    fx4 qv[4], dv[4];
    #pragma unroll
    for (int k = 0; k < 4; ++k)
        qv[k] = __builtin_nontemporal_load(&q4[base + 16 * k]);
    #pragma unroll
    for (int k = 0; k < 4; ++k)
        dv[k] = __builtin_nontemporal_load(&d4[base + 16 * k]);

    float qq = 0.0f, dd = 0.0f, qd = 0.0f;
    #pragma unroll
    for (int k = 0; k < 4; ++k) {
        qq += qv[k].x * qv[k].x + qv[k].y * qv[k].y +
              qv[k].z * qv[k].z + qv[k].w * qv[k].w;
        dd += dv[k].x * dv[k].x + dv[k].y * dv[k].y +
              dv[k].z * dv[k].z + dv[k].w * dv[k].w;
        qd += qv[k].x * dv[k].x + qv[k].y * dv[k].y +
              qv[k].z * dv[k].z + qv[k].w * dv[k].w;
    }

    // 4-step butterfly across the 16-lane group (xor masks < 16 never
    // cross the group boundary).
    #pragma unroll
    for (int off = 8; off > 0; off >>= 1) {
        qq += __shfl_xor(qq, off, 64);
        dd += __shfl_xor(dd, off, 64);
        qd += __shfl_xor(qd, off, 64);
    }

    if (c == 0) {
        // Lanes 0,16,32,48 write rows row0..row0+3: one 16 B segment.
        __builtin_nontemporal_store(qd * rsqrtf(qq * dd), &out[row]);
    }
}

extern "C" void kernel_launch(void* const* d_in, const int* in_sizes, int n_in,
                              void* d_out, int out_size, void* d_ws, size_t ws_size,
                              hipStream_t stream) {
    const fx4* q4 = (const fx4*)d_in[0];
    const fx4* d4 = (const fx4*)d_in[1];
    float* out = (float*)d_out;

    const int D = 256;
    const int n_rows = in_sizes[0] / D;   // 262144

    // 4 waves/block x 4 rows/wave = 16 rows per block.
    const int rows_per_block = WAVES_PER_BLOCK * ROWS_PER_WAVE;
    const int grid = (n_rows + rows_per_block - 1) / rows_per_block;

    cosine_rows_kernel<<<grid, 256, 0, stream>>>(q4, d4, out, n_rows);
}